// Round 13
// baseline (217.116 us; speedup 1.0000x reference)
//
#include <hip/hip_runtime.h>
#include <math.h>

#define T_LEN 512
#define H_DIM 50
#define BPB   16          // batches per block (MFMA N)
#define NW    4           // 4 waves = 1 per SIMD: no issue contention
#define TPW   3           // tiles per wave (wave 3 carries tile 12 extra, half-exec)
#define L2E   1.44269504088896f
#define XSTR  520         // halves per x-row (512 + pad so [512..515] stay in-bounds)

typedef _Float16 half8_t __attribute__((ext_vector_type(8)));
typedef float    f32x4_t __attribute__((ext_vector_type(4)));

// Device-guarded: host pass lacks the builtin (round-5 lesson).
__device__ __forceinline__ f32x4_t mfma16(half8_t a, half8_t b, f32x4_t c) {
#if defined(__HIP_DEVICE_COMPILE__)
    return __builtin_amdgcn_mfma_f32_16x16x32_f16(a, b, c, 0, 0, 0);
#else
    return c;
#endif
}
// cvt_pkrtz returns __fp16x2 -> bit_cast immediately (round-7 lesson).
__device__ __forceinline__ int pk16(float a, float b) {
    return __builtin_bit_cast(int, __builtin_amdgcn_cvt_pkrtz(a, b));
}

// Block = 256 threads = 4 waves = 16 batch elements, whole recurrence.
// gates[208 x 16] = W'[208 x 64] . H'[64 x 16] per step; rows perm
// p = 4*unit + gate -> lane-local cell update. h layout hb[buf][u>>3][b][u&7]
// (conflict-free contiguous reads). Bias in MFMA C; k=50 carries x.
// vs round 12: rounds 8-12 showed wall ~950-1010 cyc/step across issue
// 420-660/SIMD -> wall = per-wave issue + FIXED chain/barrier cost C~450.
// Fix: 1 wave/SIMD, 3 tiles/wave (wave 3: +tile 12 at half exec). B-frags
// are shared by all of a wave's tiles (2 ds_read total); 6-8 MFMA issue
// back-to-back (independent per-tile chains); 3 independent updates give
// ILP that fills the SIMD while latencies drain. Barrier syncs only 4 waves.
__global__ __launch_bounds__(NW * 64, 1) void lstm_mfma(
    const float* __restrict__ x,
    const float* __restrict__ W_ih,
    const float* __restrict__ W_hh,
    const float* __restrict__ b_ih,
    const float* __restrict__ b_hh,
    const float* __restrict__ W_fc,
    const float* __restrict__ b_fc,
    float* __restrict__ out)
{
    const int tid = threadIdx.x;
    const int w   = tid >> 6;        // wave 0..3 (SIMD w)
    const int L   = tid & 63;
    const int col = L & 15;          // batch-in-block == D-col
    const int g4  = L >> 4;          // lane group 0..3

    __shared__ _Float16 xls[BPB][XSTR];
    __shared__ __align__(16) _Float16 hb[2][8][BPB][8];  // [buf][u>>3][batch][u&7]

    // ---- stage x (16 batches x 512) f32 -> f16
    {
        const float4* xg4 = reinterpret_cast<const float4*>(
            x + (size_t)blockIdx.x * BPB * T_LEN);
        for (int f = tid; f < BPB * T_LEN / 4; f += NW * 64) {
            const float4 v = xg4[f];
            const int bb = f >> 7;               // 128 float4 per batch row
            const int c0 = (f & 127) << 2;
            *reinterpret_cast<int*>(&xls[bb][c0])     = pk16(v.x, v.y);
            *reinterpret_cast<int*>(&xls[bb][c0 + 2]) = pk16(v.z, v.w);
        }
    }
    // ---- zero both h buffers (2*8*16*8 halves = 1024 dwords)
    for (int i = tid; i < 1024; i += NW * 64) reinterpret_cast<int*>(hb)[i] = 0;
    __syncthreads();
    if (tid < BPB) hb[0][6][tid][2] = xls[tid][0];   // x_0 lives at k=50 slot

    // ---- A-fragment loader: perm row p -> (unit, gate); rows pre-scaled so
    // MFMA emits exp2-domain pre-acts (i,f,o: -L2E; g: -2*L2E).
    auto load_pair = [&](int p, half8_t& f0, half8_t& f1) {
        const int uA = p >> 2, gA = p & 3;
        const float sA = (gA == 2) ? (-2.0f * L2E) : (-L2E);
        #pragma unroll
        for (int j = 0; j < 8; ++j) {
            const int k0 = 8 * g4 + j;           // kc=0: k in [0,32)
            const int k1 = 32 + k0;              // kc=1: k in [32,64)
            float v0 = 0.0f, v1 = 0.0f;
            if (uA < H_DIM) {
                const int r = gA * H_DIM + uA;   // torch row: gate*50 + unit
                v0 = W_hh[r * H_DIM + k0];
                if (k1 < H_DIM)       v1 = W_hh[r * H_DIM + k1];
                else if (k1 == H_DIM) v1 = W_ih[r];  // k=50: x slot
            }
            f0[j] = (_Float16)(v0 * sA);
            f1[j] = (_Float16)(v1 * sA);
        }
    };
    auto load_bias = [&](int uD) -> f32x4_t {
        f32x4_t bc;
        #pragma unroll
        for (int j = 0; j < 4; ++j) {
            const float sj = (j == 2) ? (-2.0f * L2E) : (-L2E);
            bc[j] = (uD < H_DIM)
                  ? (b_ih[j * H_DIM + uD] + b_hh[j * H_DIM + uD]) * sj : 0.0f;
        }
        return bc;
    };

    // Wave w owns tiles 3w, 3w+1, 3w+2 (units 12w+4i+g4, all < 48 -> real).
    half8_t A0[TPW], A1[TPW];
    f32x4_t BC[TPW];
    _Float16* hw[TPW];
    #pragma unroll
    for (int i = 0; i < TPW; ++i) {
        const int m = TPW * w + i;
        load_pair(16 * m + col, A0[i], A1[i]);
        const int uD = 4 * m + g4;
        BC[i] = load_bias(uD);
        hw[i] = &hb[0][uD >> 3][col][uD & 7];
    }
    // Tile 12 (units 48-51; only 48,49 real) rides on wave 3, half-exec.
    half8_t T0, T1;
    f32x4_t BC3 = {0.f, 0.f, 0.f, 0.f};
    _Float16* hw3 = &hb[0][6][col][g4 & 1];      // g4=0 -> unit 48, g4=1 -> 49
    if (w == 3) {
        load_pair(192 + col, T0, T1);
        BC3 = load_bias(48 + g4);
    }

    const _Float16* rB = &hb[0][0][0][0] + (g4 * 128 + col * 8);
    const _Float16* xq = &xls[col][1];
    _Float16* xd = &hb[0][6][col][2];            // x slot (k=50), buffer 0
    const bool xw = (w == 0) && (g4 == 3);       // x-feed duty

    float c[TPW] = {0.f, 0.f, 0.f};
    float c3 = 0.0f;
    __syncthreads();

    // Merged-rcp cell update: 5 exp2 + 3 rcp (acc already exp2-domain).
    auto update = [&](const f32x4_t& acc, float& cc, _Float16* hwp, int WO) {
        const float Ei = __builtin_amdgcn_exp2f(acc[0]);
        const float Ef = __builtin_amdgcn_exp2f(acc[1]);
        const float Eg = __builtin_amdgcn_exp2f(acc[2]);
        const float Eo = __builtin_amdgcn_exp2f(acc[3]);
        const float fg  = __builtin_amdgcn_rcpf(1.0f + Ef);
        const float r1  = __builtin_amdgcn_rcpf((1.0f + Ei) * (1.0f + Eg));
        const float pig = (1.0f - Eg) * r1;      // sigmoid(i)*tanh(g)
        cc = __fmaf_rn(fg, cc, pig);
        const float Ec = __builtin_amdgcn_exp2f(cc * (-2.0f * L2E));
        const float r2 = __builtin_amdgcn_rcpf((1.0f + Ec) * (1.0f + Eo));
        const float hv = (1.0f - Ec) * r2;       // sigmoid(o)*tanh(c)
        hwp[WO] = (_Float16)hv;
    };

    // RO/WO = half-offsets for read/write buffer; XI = x index within quad.
    auto step = [&](int RO, int WO, int XI) {
        const half8_t b0 = *reinterpret_cast<const half8_t*>(rB + RO);
        const half8_t b1 = *reinterpret_cast<const half8_t*>(rB + RO + 512);
        _Float16 xn = (_Float16)0.0f;
        if (xw) xn = xq[XI];                     // prefetch: consumed later
        f32x4_t acc[TPW];
        #pragma unroll
        for (int i = 0; i < TPW; ++i) acc[i] = mfma16(A0[i], b0, BC[i]);
        #pragma unroll
        for (int i = 0; i < TPW; ++i) acc[i] = mfma16(A1[i], b1, acc[i]);
        if (w == 3) {                            // wave-uniform
            f32x4_t a3 = mfma16(T0, b0, BC3);
            a3 = mfma16(T1, b1, a3);
            if (L < 32) update(a3, c3, hw3, WO); // units 48,49 (half-exec)
        }
        #pragma unroll
        for (int i = 0; i < TPW; ++i) update(acc[i], c[i], hw[i], WO);
        if (xw) xd[WO] = xn;
        __syncthreads();
    };

    for (int t = 0; t < T_LEN; t += 4) {         // 2 buffer pairs per iter
        step(0,    1024, 0);                     // read buf0, write buf1
        step(1024, 0,    1);
        step(0,    1024, 2);
        step(1024, 0,    3);
        xq += 4;
    }

    // ---- epilogue: h_512 is in hb[0]; out[b] = h . W_fc + b_fc
    if (w == 0) {
        float part = 0.0f;
        #pragma unroll
        for (int j = 0; j < 13; ++j) {
            const int u = 13 * g4 + j;
            if (u < H_DIM)
                part += (float)hb[0][u >> 3][col][u & 7] * W_fc[u];
        }
        part += __shfl_xor(part, 16);
        part += __shfl_xor(part, 32);
        if (L < BPB) out[blockIdx.x * BPB + L] = part + b_fc[0];
    }
}

extern "C" void kernel_launch(void* const* d_in, const int* in_sizes, int n_in,
                              void* d_out, int out_size, void* d_ws, size_t ws_size,
                              hipStream_t stream) {
    const float* x    = (const float*)d_in[0];
    const float* W_ih = (const float*)d_in[1];
    const float* W_hh = (const float*)d_in[2];
    const float* b_ih = (const float*)d_in[3];
    const float* b_hh = (const float*)d_in[4];
    const float* W_fc = (const float*)d_in[5];
    const float* b_fc = (const float*)d_in[6];
    float* out = (float*)d_out;

    const int B = in_sizes[0] / T_LEN;   // 4096
    lstm_mfma<<<dim3(B / BPB), dim3(NW * 64), 0, stream>>>(
        x, W_ih, W_hh, b_ih, b_hh, W_fc, b_fc, out);
}

// Round 14
// 208.484 us; speedup vs baseline: 1.0414x; 1.0414x over previous
//
#include <hip/hip_runtime.h>
#include <math.h>

#define T_LEN 512
#define H_DIM 50
#define BPB   16          // batches per block (MFMA N)
#define NW    12          // waves: 3 per SIMD, balanced (tile 12 rides on wave 11)
#define L2E   1.44269504088896f
#define XSTR  520         // halves per x-row (512 + pad so [512..515] stay in-bounds)

typedef _Float16 half8_t __attribute__((ext_vector_type(8)));
typedef float    f32x4_t __attribute__((ext_vector_type(4)));

// Device-guarded: host pass lacks the builtin (round-5 lesson).
__device__ __forceinline__ f32x4_t mfma16(half8_t a, half8_t b, f32x4_t c) {
#if defined(__HIP_DEVICE_COMPILE__)
    return __builtin_amdgcn_mfma_f32_16x16x32_f16(a, b, c, 0, 0, 0);
#else
    return c;
#endif
}
// cvt_pkrtz returns __fp16x2 -> bit_cast immediately (round-7 lesson).
__device__ __forceinline__ int pk16(float a, float b) {
    return __builtin_bit_cast(int, __builtin_amdgcn_cvt_pkrtz(a, b));
}

// Block = 768 threads = 12 waves = 16 batch elements, whole recurrence.
// gates[208 x 16] = W'[208 x 64] . H'[64 x 16] per step; rows perm
// p = 4*unit + gate -> lane-local cell update. h layout hb[buf][u>>3][b][u&7]
// (conflict-free contiguous 1KB wave reads). Bias in MFMA C; k=50 carries x.
// r8-r13 scaling curve: wall ~950-1070 cyc/step for issue 360-660/SIMD ->
// lockstep chain (~500 cyc: post-barrier LDS burst + MFMA dep + activation
// chain + barrier skew) is the binding term. This round (r11 base = best):
// (a) INDEPENDENT MFMA pair (accA/accB, lane-add in update) — removes the
//     ~30cyc second-MFMA chain dependency;
// (b) tile-12 update exec-masked to L<32 (its real units are 48,49 only).
__global__ __launch_bounds__(NW * 64, 1) void lstm_mfma(
    const float* __restrict__ x,
    const float* __restrict__ W_ih,
    const float* __restrict__ W_hh,
    const float* __restrict__ b_ih,
    const float* __restrict__ b_hh,
    const float* __restrict__ W_fc,
    const float* __restrict__ b_fc,
    float* __restrict__ out)
{
    const int tid = threadIdx.x;
    const int w   = tid >> 6;        // wave = tile index 0..11
    const int L   = tid & 63;
    const int col = L & 15;          // batch-in-block == D-col
    const int g4  = L >> 4;          // lane group 0..3

    __shared__ _Float16 xls[BPB][XSTR];
    __shared__ __align__(16) _Float16 hb[2][8][BPB][8];  // [buf][u>>3][batch][u&7]

    // ---- stage x (16 batches x 512) f32 -> f16
    {
        const float4* xg4 = reinterpret_cast<const float4*>(
            x + (size_t)blockIdx.x * BPB * T_LEN);
        for (int f = tid; f < BPB * T_LEN / 4; f += NW * 64) {
            const float4 v = xg4[f];
            const int bb = f >> 7;               // 128 float4 per batch row
            const int c0 = (f & 127) << 2;
            *reinterpret_cast<int*>(&xls[bb][c0])     = pk16(v.x, v.y);
            *reinterpret_cast<int*>(&xls[bb][c0 + 2]) = pk16(v.z, v.w);
        }
    }
    // ---- zero both h buffers (2*8*16*8 halves = 1024 dwords)
    for (int i = tid; i < 1024; i += NW * 64) reinterpret_cast<int*>(hb)[i] = 0;
    __syncthreads();
    if (tid < BPB) hb[0][6][tid][2] = xls[tid][0];   // x_0 lives at k=50 slot

    // ---- A-fragment loader: perm row p -> (unit, gate); rows pre-scaled so
    // MFMA emits exp2-domain pre-acts (i,f,o: -L2E; g: -2*L2E).
    auto load_pair = [&](int p, half8_t& f0, half8_t& f1) {
        const int uA = p >> 2, gA = p & 3;
        const float sA = (gA == 2) ? (-2.0f * L2E) : (-L2E);
        #pragma unroll
        for (int j = 0; j < 8; ++j) {
            const int k0 = 8 * g4 + j;           // kc=0: k in [0,32)
            const int k1 = 32 + k0;              // kc=1: k in [32,64)
            float v0 = 0.0f, v1 = 0.0f;
            if (uA < H_DIM) {
                const int r = gA * H_DIM + uA;   // torch row: gate*50 + unit
                v0 = W_hh[r * H_DIM + k0];
                if (k1 < H_DIM)       v1 = W_hh[r * H_DIM + k1];
                else if (k1 == H_DIM) v1 = W_ih[r];  // k=50: x slot
            }
            f0[j] = (_Float16)(v0 * sA);
            f1[j] = (_Float16)(v1 * sA);
        }
    };
    auto load_bias = [&](int uD) -> f32x4_t {
        f32x4_t bc;
        #pragma unroll
        for (int j = 0; j < 4; ++j) {
            const float sj = (j == 2) ? (-2.0f * L2E) : (-L2E);
            bc[j] = (uD < H_DIM)
                  ? (b_ih[j * H_DIM + uD] + b_hh[j * H_DIM + uD]) * sj : 0.0f;
        }
        return bc;
    };
    half8_t a0, a1, a20, a21;
    load_pair(16 * w + col, a0, a1);
    load_pair(192 + col, a20, a21);              // tile 12 (used by wave 11 only)

    const int uD1 = 4 * w + g4;                  // tiles 0..11: always real (<48)
    const int uD2 = 48 + g4;                     // tile 12: real for g4<2
    const f32x4_t biasC1 = load_bias(uD1);
    const f32x4_t biasC2 = load_bias(uD2);

    // Precomputed write pointers (junk slots k=52/53 for tile-12 fakes).
    const int uD2w = (uD2 < H_DIM) ? uD2 : (52 + (uD2 & 1));
    _Float16* hw1 = &hb[0][uD1 >> 3][col][uD1 & 7];
    _Float16* hw2 = &hb[0][uD2w >> 3][col][uD2w & 7];
    const _Float16* rB = &hb[0][0][0][0] + (g4 * 128 + col * 8);
    const _Float16* xq = &xls[col][1];
    _Float16* xd = &hb[0][6][col][2];            // x slot (k=50), buffer 0
    const bool xw  = (w == 9) && (g4 == 3);      // x-feed: SIMD1 (i%4), light wave
    const bool two = (w == 11);                  // tile-12 carrier (SIMD3)

    float c1 = 0.0f, c2 = 0.0f;
    const f32x4_t zero4 = {0.0f, 0.0f, 0.0f, 0.0f};
    __syncthreads();

    // Merged-rcp cell update; takes the two independent MFMA partial sums and
    // combines lane-wise (the adds replace the second MFMA's chain dependency).
    auto update = [&](const f32x4_t& pa, const f32x4_t& pb,
                      float& c, _Float16* hw, int WO) {
        const float Ei = __builtin_amdgcn_exp2f(pa[0] + pb[0]);
        const float Ef = __builtin_amdgcn_exp2f(pa[1] + pb[1]);
        const float Eg = __builtin_amdgcn_exp2f(pa[2] + pb[2]);
        const float Eo = __builtin_amdgcn_exp2f(pa[3] + pb[3]);
        const float fg  = __builtin_amdgcn_rcpf(1.0f + Ef);
        const float r1  = __builtin_amdgcn_rcpf((1.0f + Ei) * (1.0f + Eg));
        const float pig = (1.0f - Eg) * r1;      // sigmoid(i)*tanh(g)
        c = __fmaf_rn(fg, c, pig);
        const float Ec = __builtin_amdgcn_exp2f(c * (-2.0f * L2E));
        const float r2 = __builtin_amdgcn_rcpf((1.0f + Ec) * (1.0f + Eo));
        const float hv = (1.0f - Ec) * r2;       // sigmoid(o)*tanh(c)
        hw[WO] = (_Float16)hv;
    };

    // RO/WO = half-offsets for read/write buffer; XI = x index within quad.
    auto step = [&](int RO, int WO, int XI) {
        const half8_t b0 = *reinterpret_cast<const half8_t*>(rB + RO);
        const half8_t b1 = *reinterpret_cast<const half8_t*>(rB + RO + 512);
        _Float16 xn = (_Float16)0.0f;
        if (xw) xn = xq[XI];                     // prefetch: consumed ~200cyc later
        const f32x4_t accA = mfma16(a0, b0, biasC1);  // independent pair
        const f32x4_t accB = mfma16(a1, b1, zero4);
        update(accA, accB, c1, hw1, WO);
        if (two) {                               // wave-uniform branch
            const f32x4_t pA = mfma16(a20, b0, biasC2);
            const f32x4_t pB = mfma16(a21, b1, zero4);
            if (L < 32) update(pA, pB, c2, hw2, WO);  // units 48,49 (half-exec)
        }
        if (xw) xd[WO] = xn;
        __syncthreads();
    };

    for (int t = 0; t < T_LEN; t += 4) {         // 2 buffer pairs per iter
        step(0,    1024, 0);                     // read buf0, write buf1
        step(1024, 0,    1);
        step(0,    1024, 2);
        step(1024, 0,    3);
        xq += 4;
    }

    // ---- epilogue: h_512 is in hb[0]; out[b] = h . W_fc + b_fc
    if (w == 0) {
        float part = 0.0f;
        #pragma unroll
        for (int j = 0; j < 13; ++j) {
            const int u = 13 * g4 + j;
            if (u < H_DIM)
                part += (float)hb[0][u >> 3][col][u & 7] * W_fc[u];
        }
        part += __shfl_xor(part, 16);
        part += __shfl_xor(part, 32);
        if (L < BPB) out[blockIdx.x * BPB + L] = part + b_fc[0];
    }
}

extern "C" void kernel_launch(void* const* d_in, const int* in_sizes, int n_in,
                              void* d_out, int out_size, void* d_ws, size_t ws_size,
                              hipStream_t stream) {
    const float* x    = (const float*)d_in[0];
    const float* W_ih = (const float*)d_in[1];
    const float* W_hh = (const float*)d_in[2];
    const float* b_ih = (const float*)d_in[3];
    const float* b_hh = (const float*)d_in[4];
    const float* W_fc = (const float*)d_in[5];
    const float* b_fc = (const float*)d_in[6];
    float* out = (float*)d_out;

    const int B = in_sizes[0] / T_LEN;   // 4096
    lstm_mfma<<<dim3(B / BPB), dim3(NW * 64), 0, stream>>>(
        x, W_ih, W_hh, b_ih, b_hh, W_fc, b_fc, out);
}

// Round 15
// 193.685 us; speedup vs baseline: 1.1210x; 1.0764x over previous
//
#include <hip/hip_runtime.h>
#include <math.h>

#define T_LEN 512
#define H_DIM 50
#define BPB   16          // batches per block (MFMA N)
#define NW    12          // waves: 3 per SIMD, balanced (tile 12 rides on wave 11)
#define L2E   1.44269504088896f
#define XSTR  520         // halves per x-row (512 + pad so [512..515] stay in-bounds)

typedef _Float16 half8_t __attribute__((ext_vector_type(8)));
typedef float    f32x4_t __attribute__((ext_vector_type(4)));

// Device-guarded: host pass lacks the builtin (round-5 lesson).
__device__ __forceinline__ f32x4_t mfma16(half8_t a, half8_t b, f32x4_t c) {
#if defined(__HIP_DEVICE_COMPILE__)
    return __builtin_amdgcn_mfma_f32_16x16x32_f16(a, b, c, 0, 0, 0);
#else
    return c;
#endif
}
// cvt_pkrtz returns __fp16x2 -> bit_cast immediately (round-7 lesson).
__device__ __forceinline__ int pk16(float a, float b) {
    return __builtin_bit_cast(int, __builtin_amdgcn_cvt_pkrtz(a, b));
}

// Block = 768 threads = 12 waves = 16 batch elements, whole recurrence.
// gates[208 x 16] = W'[208 x 64] . H'[64 x 16] per step; rows perm
// p = 4*unit + gate -> lane-local cell update. h layout hb[buf][u>>3][b][u&7]
// (conflict-free contiguous 1KB wave reads). Bias in MFMA C; k=50 carries x.
// BEST-MEASURED configuration (r11: 190 us bench / 943 cyc/step).
// r8-r14 scaling curve: wall 940-1070 cyc/step across waves {4,12,13} and
// issue 360-660 cyc/SIMD -> binding term is the lockstep chain (~470 cyc:
// per-CU LDS broadcast burst ~290 + MFMA dep + activation chain + barrier
// skew) on top of ~470 issue. Chain-trim attempts (r13/r14) both regressed:
// every added instruction lands ON the critical chain; compiler scheduling
// of this chained form is near-optimal.
__global__ __launch_bounds__(NW * 64, 1) void lstm_mfma(
    const float* __restrict__ x,
    const float* __restrict__ W_ih,
    const float* __restrict__ W_hh,
    const float* __restrict__ b_ih,
    const float* __restrict__ b_hh,
    const float* __restrict__ W_fc,
    const float* __restrict__ b_fc,
    float* __restrict__ out)
{
    const int tid = threadIdx.x;
    const int w   = tid >> 6;        // wave = tile index 0..11
    const int L   = tid & 63;
    const int col = L & 15;          // batch-in-block == D-col
    const int g4  = L >> 4;          // lane group 0..3

    __shared__ _Float16 xls[BPB][XSTR];
    __shared__ __align__(16) _Float16 hb[2][8][BPB][8];  // [buf][u>>3][batch][u&7]

    // ---- stage x (16 batches x 512) f32 -> f16
    {
        const float4* xg4 = reinterpret_cast<const float4*>(
            x + (size_t)blockIdx.x * BPB * T_LEN);
        for (int f = tid; f < BPB * T_LEN / 4; f += NW * 64) {
            const float4 v = xg4[f];
            const int bb = f >> 7;               // 128 float4 per batch row
            const int c0 = (f & 127) << 2;
            *reinterpret_cast<int*>(&xls[bb][c0])     = pk16(v.x, v.y);
            *reinterpret_cast<int*>(&xls[bb][c0 + 2]) = pk16(v.z, v.w);
        }
    }
    // ---- zero both h buffers (2*8*16*8 halves = 1024 dwords)
    for (int i = tid; i < 1024; i += NW * 64) reinterpret_cast<int*>(hb)[i] = 0;
    __syncthreads();
    if (tid < BPB) hb[0][6][tid][2] = xls[tid][0];   // x_0 lives at k=50 slot

    // ---- A-fragment loader: perm row p -> (unit, gate); rows pre-scaled so
    // MFMA emits exp2-domain pre-acts (i,f,o: -L2E; g: -2*L2E).
    auto load_pair = [&](int p, half8_t& f0, half8_t& f1) {
        const int uA = p >> 2, gA = p & 3;
        const float sA = (gA == 2) ? (-2.0f * L2E) : (-L2E);
        #pragma unroll
        for (int j = 0; j < 8; ++j) {
            const int k0 = 8 * g4 + j;           // kc=0: k in [0,32)
            const int k1 = 32 + k0;              // kc=1: k in [32,64)
            float v0 = 0.0f, v1 = 0.0f;
            if (uA < H_DIM) {
                const int r = gA * H_DIM + uA;   // torch row: gate*50 + unit
                v0 = W_hh[r * H_DIM + k0];
                if (k1 < H_DIM)       v1 = W_hh[r * H_DIM + k1];
                else if (k1 == H_DIM) v1 = W_ih[r];  // k=50: x slot
            }
            f0[j] = (_Float16)(v0 * sA);
            f1[j] = (_Float16)(v1 * sA);
        }
    };
    half8_t a0, a1, a20, a21;
    load_pair(16 * w + col, a0, a1);
    load_pair(192 + col, a20, a21);              // tile 12 (used by wave 11 only)

    // ---- D-side bias (pre-scaled), tile 1 and tile 2
    auto load_bias = [&](int uD) -> f32x4_t {
        f32x4_t bc;
        #pragma unroll
        for (int j = 0; j < 4; ++j) {
            const float sj = (j == 2) ? (-2.0f * L2E) : (-L2E);
            bc[j] = (uD < H_DIM)
                  ? (b_ih[j * H_DIM + uD] + b_hh[j * H_DIM + uD]) * sj : 0.0f;
        }
        return bc;
    };
    const int uD1 = 4 * w + g4;                  // tiles 0..11: always real (<48)
    const int uD2 = 48 + g4;                     // tile 12: real for g4<2
    const f32x4_t biasC1 = load_bias(uD1);
    const f32x4_t biasC2 = load_bias(uD2);

    // Precomputed write pointers (junk slots k=52/53 for tile-12 fakes).
    const int uD2w = (uD2 < H_DIM) ? uD2 : (52 + (uD2 & 1));
    _Float16* hw1 = &hb[0][uD1 >> 3][col][uD1 & 7];
    _Float16* hw2 = &hb[0][uD2w >> 3][col][uD2w & 7];
    const _Float16* rB = &hb[0][0][0][0] + (g4 * 128 + col * 8);
    const _Float16* xq = &xls[col][1];
    _Float16* xd = &hb[0][6][col][2];            // x slot (k=50), buffer 0
    const bool xw  = (w == 9) && (g4 == 3);      // x-feed: SIMD1 (i%4), light wave
    const bool two = (w == 11);                  // tile-12 carrier (SIMD3)

    float c1 = 0.0f, c2 = 0.0f;
    __syncthreads();

    // Merged-rcp cell update: 5 exp2 + 3 rcp (acc already exp2-domain).
    auto update = [&](const f32x4_t& acc, float& c, _Float16* hw, int WO) {
        const float Ei = __builtin_amdgcn_exp2f(acc[0]);
        const float Ef = __builtin_amdgcn_exp2f(acc[1]);
        const float Eg = __builtin_amdgcn_exp2f(acc[2]);
        const float Eo = __builtin_amdgcn_exp2f(acc[3]);
        const float fg  = __builtin_amdgcn_rcpf(1.0f + Ef);
        const float r1  = __builtin_amdgcn_rcpf((1.0f + Ei) * (1.0f + Eg));
        const float pig = (1.0f - Eg) * r1;      // sigmoid(i)*tanh(g)
        c = __fmaf_rn(fg, c, pig);
        const float Ec = __builtin_amdgcn_exp2f(c * (-2.0f * L2E));
        const float r2 = __builtin_amdgcn_rcpf((1.0f + Ec) * (1.0f + Eo));
        const float hv = (1.0f - Ec) * r2;       // sigmoid(o)*tanh(c)
        hw[WO] = (_Float16)hv;
    };

    // RO/WO = half-offsets for read/write buffer; XI = x index within quad.
    auto step = [&](int RO, int WO, int XI) {
        const half8_t b0 = *reinterpret_cast<const half8_t*>(rB + RO);
        const half8_t b1 = *reinterpret_cast<const half8_t*>(rB + RO + 512);
        _Float16 xn = (_Float16)0.0f;
        if (xw) xn = xq[XI];                     // prefetch: consumed ~200cyc later
        f32x4_t acc = mfma16(a0, b0, biasC1);    // C = bias (D != C, no init)
        acc = mfma16(a1, b1, acc);
        update(acc, c1, hw1, WO);
        if (two) {                               // wave-uniform branch
            f32x4_t acc2 = mfma16(a20, b0, biasC2);
            acc2 = mfma16(a21, b1, acc2);
            update(acc2, c2, hw2, WO);
        }
        if (xw) xd[WO] = xn;
        __syncthreads();
    };

    for (int t = 0; t < T_LEN; t += 4) {         // 2 buffer pairs per iter
        step(0,    1024, 0);                     // read buf0, write buf1
        step(1024, 0,    1);
        step(0,    1024, 2);
        step(1024, 0,    3);
        xq += 4;
    }

    // ---- epilogue: h_512 is in hb[0]; out[b] = h . W_fc + b_fc
    if (w == 0) {
        float part = 0.0f;
        #pragma unroll
        for (int j = 0; j < 13; ++j) {
            const int u = 13 * g4 + j;
            if (u < H_DIM)
                part += (float)hb[0][u >> 3][col][u & 7] * W_fc[u];
        }
        part += __shfl_xor(part, 16);
        part += __shfl_xor(part, 32);
        if (L < BPB) out[blockIdx.x * BPB + L] = part + b_fc[0];
    }
}

extern "C" void kernel_launch(void* const* d_in, const int* in_sizes, int n_in,
                              void* d_out, int out_size, void* d_ws, size_t ws_size,
                              hipStream_t stream) {
    const float* x    = (const float*)d_in[0];
    const float* W_ih = (const float*)d_in[1];
    const float* W_hh = (const float*)d_in[2];
    const float* b_ih = (const float*)d_in[3];
    const float* b_hh = (const float*)d_in[4];
    const float* W_fc = (const float*)d_in[5];
    const float* b_fc = (const float*)d_in[6];
    float* out = (float*)d_out;

    const int B = in_sizes[0] / T_LEN;   // 4096
    lstm_mfma<<<dim3(B / BPB), dim3(NW * 64), 0, stream>>>(
        x, W_ih, W_hh, b_ih, b_hh, W_fc, b_fc, out);
}